// Round 11
// baseline (29.229 us; speedup 1.0000x reference)
//
#include <hip/hip_runtime.h>
#include <hip/hip_bf16.h>
#include <cstdint>

#define DIM 128
#define PSTR 132   // part[] row stride: 128+4 pad -> 2-way (free) bank access

__device__ __forceinline__ float prelu(float x, float a) {
    return x >= 0.f ? x : a * x;
}

// ---- per-thread weight fragment: 12 floats, PRIVATE to thread (k,u) ----
// Chunk c covers d in [32c,32c+32); thread (k,u) owns d-slice [32c+4u, +4),
// i.e. floats W[k*768 + c*96 + u*12 .. +11]. No LDS, no swizzle, no asm.
__device__ __forceinline__ void load_w3(const float* __restrict__ W, int c,
                                        int k, int u, float4 w[3]) {
    const float* p = W + (size_t)k * 768 + c * 96 + u * 12;
    w[0] = *reinterpret_cast<const float4*>(p);
    w[1] = *reinterpret_cast<const float4*>(p + 4);
    w[2] = *reinterpret_cast<const float4*>(p + 8);
}

// One 32-d chunk of bilinear accumulation from register weights.
// (Identical math to round 10, which passed bit-exact.)
template<int J>
__device__ __forceinline__ void bilin_chunk_reg(const float4 w[3], int c,
                                                const float* xbase, int u,
                                                float acc[][3]) {
    const float wf[12] = { w[0].x, w[0].y, w[0].z, w[0].w,
                           w[1].x, w[1].y, w[1].z, w[1].w,
                           w[2].x, w[2].y, w[2].z, w[2].w };
    const int inner = ((c & 3) << 5) + (u << 2);
    const int half = c >> 2;   // which 128-row of the 256-wide concat
#pragma unroll
    for (int j = 0; j < J; ++j) {
        float4 xv = *reinterpret_cast<const float4*>(
            xbase + (2 * j + half) * 128 + inner);
        const float xf[4] = { xv.x, xv.y, xv.z, xv.w };
#pragma unroll
        for (int dl = 0; dl < 4; ++dl)
#pragma unroll
            for (int v = 0; v < 3; ++v)
                acc[j][v] += wf[dl * 3 + v] * xf[dl];
    }
}

// Round-10 epilogue (pairwise tree), part stride padded to PSTR.
template<int ROWS>
__device__ __forceinline__ void reduce_part(const float* part, float biasv,
                                            float aval, float* dst, int t) {
    if (t < ROWS * 128) {
        int r = t >> 7, kk = t & 127;
        float p0 = part[(0 * ROWS + r) * PSTR + kk];
        float p1 = part[(1 * ROWS + r) * PSTR + kk];
        float p2 = part[(2 * ROWS + r) * PSTR + kk];
        float p3 = part[(3 * ROWS + r) * PSTR + kk];
        float p4 = part[(4 * ROWS + r) * PSTR + kk];
        float p5 = part[(5 * ROWS + r) * PSTR + kk];
        float p6 = part[(6 * ROWS + r) * PSTR + kk];
        float p7 = part[(7 * ROWS + r) * PSTR + kk];
        float s = ((p0 + p1) + (p2 + p3)) + ((p4 + p5) + (p6 + p7));
        dst[r * 128 + kk] = prelu(s + biasv, aval);
    }
}

// Sampled linear with PRELOADED weight registers (wv loaded in prologue).
template<int NODES>
__device__ __forceinline__ void linear_stage_pre(const float4* wv,
                                                 const float* const* x0,
                                                 const float* const* x1,
                                                 float* part, int k, int u) {
#pragma unroll
    for (int n = 0; n < NODES; ++n) {
        float acc = 0.f;
#pragma unroll
        for (int i = 0; i < 8; ++i) {
            const float* xr = (i < 4) ? (x0[n] + (i << 5) + (u << 2))
                                      : (x1[n] + ((i - 4) << 5) + (u << 2));
            float4 xv = *reinterpret_cast<const float4*>(xr);
            acc += wv[i].x * xv.x + wv[i].y * xv.y + wv[i].z * xv.z + wv[i].w * xv.w;
        }
        part[(u * NODES + n) * PSTR + k] = acc;
    }
}

__global__ __launch_bounds__(1024) void encoder_fused(
    const float* __restrict__ points,
    const float* __restrict__ vec2, const float* __restrict__ vec1,
    const float* __restrict__ vec0,
    const float* __restrict__ Wp,  const float* __restrict__ bp,
    const float* __restrict__ aL,
    const float* __restrict__ Wb2, const float* __restrict__ bb2,
    const float* __restrict__ a2,
    const float* __restrict__ Wb1, const float* __restrict__ bb1,
    const float* __restrict__ Ws1, const float* __restrict__ bs1,
    const float* __restrict__ a1,
    const float* __restrict__ Wb0, const float* __restrict__ bb0,
    const float* __restrict__ Ws0, const float* __restrict__ bs0,
    const float* __restrict__ a0,
    const int* __restrict__ cl2, const int* __restrict__ cr2,
    const int* __restrict__ cl1, const int* __restrict__ cr1,
    const int* __restrict__ cs1,
    const int* __restrict__ cl0, const int* __restrict__ cr0,
    const int* __restrict__ cs0,
    float* __restrict__ out,
    int N3, int N2, int N1)
{
    __shared__ float leaf[12][DIM];
    __shared__ float h2s[5][DIM];
    __shared__ float t1s[2][DIM];
    __shared__ float h1s[2][DIM];
    __shared__ float h0s[DIM];
    __shared__ float part[8 * 5 * PSTR];
    __shared__ int   ljs[12];

    const int b = blockIdx.x;
    const int t = threadIdx.x;
    const int k  = t >> 3;    // output channel 0..127
    const int u  = t & 7;     // d-subchunk 0..7
    const int kk = t & 127;

    // ---- uniform index chain ----
    const int m0 = cl0[0], m1 = cr0[0];
    int nj[5];
    nj[0] = cl1[m0]; nj[1] = cr1[m0];
    nj[2] = cl1[m1]; nj[3] = cr1[m1];
    nj[4] = cs0[0];
    if (t == 0) {
        ljs[0] = cl2[nj[0]]; ljs[1] = cr2[nj[0]];
        ljs[2] = cl2[nj[1]]; ljs[3] = cr2[nj[1]];
        ljs[4] = cl2[nj[2]]; ljs[5] = cr2[nj[2]];
        ljs[6] = cl2[nj[3]]; ljs[7] = cr2[nj[3]];
        ljs[8] = cl2[nj[4]]; ljs[9] = cr2[nj[4]];
        ljs[10] = cs1[m0];   ljs[11] = cs1[m1];
    }

    // ---- preloads (scalars, vec triplets) ----
    const float aLv = aL[0], a2v = a2[0], a1v = a1[0], a0v = a0[0];
    const float wp0 = Wp[kk * 3 + 0], wp1 = Wp[kk * 3 + 1], wp2 = Wp[kk * 3 + 2];
    const float bpv = bp[kk];
    const float bb2v = bb2[kk], bb1v = bb1[kk], bs1v = bs1[kk];
    const float bb0v = bb0[kk], bs0v = bs0[kk];
    float v2r[5][3], v1r[2][3], v0r[3];
#pragma unroll
    for (int j = 0; j < 5; ++j) {
        size_t vb = ((size_t)b * N2 + nj[j]) * 3;
        v2r[j][0] = vec2[vb]; v2r[j][1] = vec2[vb + 1]; v2r[j][2] = vec2[vb + 2];
    }
    {
        size_t vb0 = ((size_t)b * N1 + m0) * 3, vb1 = ((size_t)b * N1 + m1) * 3;
        v1r[0][0] = vec1[vb0]; v1r[0][1] = vec1[vb0 + 1]; v1r[0][2] = vec1[vb0 + 2];
        v1r[1][0] = vec1[vb1]; v1r[1][1] = vec1[vb1 + 1]; v1r[1][2] = vec1[vb1 + 2];
    }
    v0r[0] = vec0[b * 3]; v0r[1] = vec0[b * 3 + 1]; v0r[2] = vec0[b * 3 + 2];

    // ---- preload sampled-linear weights (used at layer boundaries) ----
    float4 ws1v[8], ws0v[8];
#pragma unroll
    for (int i = 0; i < 8; ++i) {
        ws1v[i] = *reinterpret_cast<const float4*>(Ws1 + k * 256 + ((i * 8 + u) << 2));
        ws0v[i] = *reinterpret_cast<const float4*>(Ws0 + k * 256 + ((i * 8 + u) << 2));
    }

    // ---- depth-3 weight pipeline: 4 rotating register slots, all static ----
    float4 w[4][3];
    load_w3(Wb2, 0, k, u, w[0]);
    load_w3(Wb2, 1, k, u, w[1]);
    load_w3(Wb2, 2, k, u, w[2]);

    __syncthreads();                      // ljs visible

    // ---- leaf rows ----
    for (int idx = t; idx < 12 * DIM; idx += 1024) {
        int r = idx >> 7;
        size_t pb = ((size_t)b * N3 + ljs[r]) * 3;
        float p0 = points[pb], p1 = points[pb + 1], p2 = points[pb + 2];
        leaf[r][kk] = prelu(p0 * wp0 + p1 * wp1 + p2 * wp2 + bpv, aLv);
    }
    __syncthreads();                      // leaf visible

    // ================ layer 2: 5 nodes (global chunks 0..7) =================
    float acc2[5][3] = {};
#pragma unroll
    for (int c = 0; c < 8; ++c) {
        if (c < 5) load_w3(Wb2, c + 3, k, u, w[(c + 3) & 3]);
        else       load_w3(Wb1, c - 5, k, u, w[(c + 3) & 3]);  // cross-layer
        bilin_chunk_reg<5>(w[c & 3], c, &leaf[0][0], u, acc2);
    }
#pragma unroll
    for (int j = 0; j < 5; ++j) {
        float z = v2r[j][0] * acc2[j][0] + v2r[j][1] * acc2[j][1] +
                  v2r[j][2] * acc2[j][2];
        part[(u * 5 + j) * PSTR + k] = z;
    }
    __syncthreads();
    reduce_part<5>(part, bb2v, a2v, &h2s[0][0], t);
    __syncthreads();

    // ================ layer 1 bilinear: 2 nodes (chunks 8..15) ==============
    float acc1[2][3] = {};
#pragma unroll
    for (int c = 0; c < 8; ++c) {
        if (c < 5) load_w3(Wb1, c + 3, k, u, w[(c + 3) & 3]);
        else       load_w3(Wb0, c - 5, k, u, w[(c + 3) & 3]);  // prefetch root
        bilin_chunk_reg<2>(w[c & 3], c, &h2s[0][0], u, acc1);
    }
#pragma unroll
    for (int n = 0; n < 2; ++n) {
        float z = v1r[n][0] * acc1[n][0] + v1r[n][1] * acc1[n][1] +
                  v1r[n][2] * acc1[n][2];
        part[(u * 2 + n) * PSTR + k] = z;
    }
    __syncthreads();
    reduce_part<2>(part, bb1v, a1v, &t1s[0][0], t);
    __syncthreads();

    // ---- layer 1 sampled linear (register weights, preloaded) ----
    {
        const float* x0[2] = { &t1s[0][0], &t1s[1][0] };
        const float* x1[2] = { &leaf[10][0], &leaf[11][0] };
        linear_stage_pre<2>(ws1v, x0, x1, part, k, u);
    }
    __syncthreads();
    reduce_part<2>(part, bs1v, a1v, &h1s[0][0], t);
    __syncthreads();

    // ================ root bilinear: 1 node (chunks 16..23) =================
    float acc0[1][3] = {};
#pragma unroll
    for (int c = 0; c < 8; ++c) {
        if (c < 5) load_w3(Wb0, c + 3, k, u, w[(c + 3) & 3]);
        bilin_chunk_reg<1>(w[c & 3], c, &h1s[0][0], u, acc0);
    }
    {
        float z = v0r[0] * acc0[0][0] + v0r[1] * acc0[0][1] + v0r[2] * acc0[0][2];
        part[u * PSTR + k] = z;
    }
    __syncthreads();
    reduce_part<1>(part, bb0v, a0v, &h0s[0], t);
    __syncthreads();

    // ---- root sampled linear -> output ----
    {
        const float* x0[1] = { &h0s[0] };
        const float* x1[1] = { &h2s[4][0] };
        linear_stage_pre<1>(ws0v, x0, x1, part, k, u);
    }
    __syncthreads();
    if (t < DIM) {
        float p0 = part[0 * PSTR + t], p1 = part[1 * PSTR + t];
        float p2 = part[2 * PSTR + t], p3 = part[3 * PSTR + t];
        float p4 = part[4 * PSTR + t], p5 = part[5 * PSTR + t];
        float p6 = part[6 * PSTR + t], p7 = part[7 * PSTR + t];
        float s = ((p0 + p1) + (p2 + p3)) + ((p4 + p5) + (p6 + p7));
        out[(size_t)b * DIM + t] = prelu(s + bs0v, a0v);
    }
}

// ---------------- launch ---------------------------------------------------
extern "C" void kernel_launch(void* const* d_in, const int* in_sizes, int n_in,
                              void* d_out, int out_size, void* d_ws, size_t ws_size,
                              hipStream_t stream)
{
    const float* points = (const float*)d_in[0];
    const float* vec2   = (const float*)d_in[1];
    const float* vec1   = (const float*)d_in[2];
    const float* vec0   = (const float*)d_in[3];
    const float* Wp     = (const float*)d_in[4];
    const float* bp     = (const float*)d_in[5];
    const float* a_leaf = (const float*)d_in[6];
    const float* Wb2    = (const float*)d_in[7];
    const float* bb2    = (const float*)d_in[8];
    const float* a2     = (const float*)d_in[9];
    const float* Wb1    = (const float*)d_in[10];
    const float* bb1    = (const float*)d_in[11];
    const float* Ws1    = (const float*)d_in[12];
    const float* bs1    = (const float*)d_in[13];
    const float* a1     = (const float*)d_in[14];
    const float* Wb0    = (const float*)d_in[15];
    const float* bb0    = (const float*)d_in[16];
    const float* Ws0    = (const float*)d_in[17];
    const float* bs0    = (const float*)d_in[18];
    const float* a0     = (const float*)d_in[19];
    const int* cl2 = (const int*)d_in[20];
    const int* cr2 = (const int*)d_in[21];
    const int* cl1 = (const int*)d_in[22];
    const int* cr1 = (const int*)d_in[23];
    const int* cs1 = (const int*)d_in[24];
    const int* cl0 = (const int*)d_in[25];
    const int* cr0 = (const int*)d_in[26];
    const int* cs0 = (const int*)d_in[27];

    const int B = 8, N3 = 131072, N2 = 65536, N1 = 1024;
    (void)d_ws; (void)ws_size; (void)in_sizes; (void)n_in; (void)out_size;

    encoder_fused<<<B, 1024, 0, stream>>>(
        points, vec2, vec1, vec0,
        Wp, bp, a_leaf,
        Wb2, bb2, a2,
        Wb1, bb1, Ws1, bs1, a1,
        Wb0, bb0, Ws0, bs0, a0,
        cl2, cr2, cl1, cr1, cs1, cl0, cr0, cs0,
        (float*)d_out, N3, N2, N1);
}

// Round 12
// 29.168 us; speedup vs baseline: 1.0021x; 1.0021x over previous
//
#include <hip/hip_runtime.h>
#include <hip/hip_bf16.h>
#include <cstdint>

#define DIM 128
#define PSTR 132   // part[] row stride: 128+4 pad -> 2-way (free) bank access

__device__ __forceinline__ float prelu(float x, float a) {
    return x >= 0.f ? x : a * x;
}

// ---- per-thread weight fragment: 12 floats, PRIVATE to thread (k,u) ----
// Chunk c covers d in [32c,32c+32); thread (k,u) owns d-slice [32c+4u, +4),
// i.e. floats W[k*768 + c*96 + u*12 .. +11]. No LDS, no swizzle, no asm.
__device__ __forceinline__ void load_w3(const float* __restrict__ W, int c,
                                        int k, int u, float4 w[3]) {
    const float* p = W + (size_t)k * 768 + c * 96 + u * 12;
    w[0] = *reinterpret_cast<const float4*>(p);
    w[1] = *reinterpret_cast<const float4*>(p + 4);
    w[2] = *reinterpret_cast<const float4*>(p + 8);
}

// One 32-d chunk of bilinear accumulation from register weights.
// (Identical math to round 10, which passed bit-exact.)
template<int J>
__device__ __forceinline__ void bilin_chunk_reg(const float4 w[3], int c,
                                                const float* xbase, int u,
                                                float acc[][3]) {
    const float wf[12] = { w[0].x, w[0].y, w[0].z, w[0].w,
                           w[1].x, w[1].y, w[1].z, w[1].w,
                           w[2].x, w[2].y, w[2].z, w[2].w };
    const int inner = ((c & 3) << 5) + (u << 2);
    const int half = c >> 2;   // which 128-row of the 256-wide concat
#pragma unroll
    for (int j = 0; j < J; ++j) {
        float4 xv = *reinterpret_cast<const float4*>(
            xbase + (2 * j + half) * 128 + inner);
        const float xf[4] = { xv.x, xv.y, xv.z, xv.w };
#pragma unroll
        for (int dl = 0; dl < 4; ++dl)
#pragma unroll
            for (int v = 0; v < 3; ++v)
                acc[j][v] += wf[dl * 3 + v] * xf[dl];
    }
}

// Round-10 epilogue (pairwise tree), part stride padded to PSTR.
template<int ROWS>
__device__ __forceinline__ void reduce_part(const float* part, float biasv,
                                            float aval, float* dst, int t) {
    if (t < ROWS * 128) {
        int r = t >> 7, kk = t & 127;
        float p0 = part[(0 * ROWS + r) * PSTR + kk];
        float p1 = part[(1 * ROWS + r) * PSTR + kk];
        float p2 = part[(2 * ROWS + r) * PSTR + kk];
        float p3 = part[(3 * ROWS + r) * PSTR + kk];
        float p4 = part[(4 * ROWS + r) * PSTR + kk];
        float p5 = part[(5 * ROWS + r) * PSTR + kk];
        float p6 = part[(6 * ROWS + r) * PSTR + kk];
        float p7 = part[(7 * ROWS + r) * PSTR + kk];
        float s = ((p0 + p1) + (p2 + p3)) + ((p4 + p5) + (p6 + p7));
        dst[r * 128 + kk] = prelu(s + biasv, aval);
    }
}

// Sampled linear with PRELOADED weight registers (wv loaded in prologue).
template<int NODES>
__device__ __forceinline__ void linear_stage_pre(const float4* wv,
                                                 const float* const* x0,
                                                 const float* const* x1,
                                                 float* part, int k, int u) {
#pragma unroll
    for (int n = 0; n < NODES; ++n) {
        float acc = 0.f;
#pragma unroll
        for (int i = 0; i < 8; ++i) {
            const float* xr = (i < 4) ? (x0[n] + (i << 5) + (u << 2))
                                      : (x1[n] + ((i - 4) << 5) + (u << 2));
            float4 xv = *reinterpret_cast<const float4*>(xr);
            acc += wv[i].x * xv.x + wv[i].y * xv.y + wv[i].z * xv.z + wv[i].w * xv.w;
        }
        part[(u * NODES + n) * PSTR + k] = acc;
    }
}

__global__ __launch_bounds__(1024) void encoder_fused(
    const float* __restrict__ points,
    const float* __restrict__ vec2, const float* __restrict__ vec1,
    const float* __restrict__ vec0,
    const float* __restrict__ Wp,  const float* __restrict__ bp,
    const float* __restrict__ aL,
    const float* __restrict__ Wb2, const float* __restrict__ bb2,
    const float* __restrict__ a2,
    const float* __restrict__ Wb1, const float* __restrict__ bb1,
    const float* __restrict__ Ws1, const float* __restrict__ bs1,
    const float* __restrict__ a1,
    const float* __restrict__ Wb0, const float* __restrict__ bb0,
    const float* __restrict__ Ws0, const float* __restrict__ bs0,
    const float* __restrict__ a0,
    const int* __restrict__ cl2, const int* __restrict__ cr2,
    const int* __restrict__ cl1, const int* __restrict__ cr1,
    const int* __restrict__ cs1,
    const int* __restrict__ cl0, const int* __restrict__ cr0,
    const int* __restrict__ cs0,
    float* __restrict__ out,
    int N3, int N2, int N1)
{
    __shared__ float leaf[12][DIM];
    __shared__ float h2s[5][DIM];
    __shared__ float t1s[2][DIM];
    __shared__ float h1s[2][DIM];
    __shared__ float h0s[DIM];
    __shared__ float part[8 * 5 * PSTR];
    __shared__ int   ljs[12];

    const int b = blockIdx.x;
    const int t = threadIdx.x;
    const int k  = t >> 3;    // output channel 0..127
    const int u  = t & 7;     // d-subchunk 0..7
    const int kk = t & 127;

    // ---- uniform index chain ----
    const int m0 = cl0[0], m1 = cr0[0];
    int nj[5];
    nj[0] = cl1[m0]; nj[1] = cr1[m0];
    nj[2] = cl1[m1]; nj[3] = cr1[m1];
    nj[4] = cs0[0];
    if (t == 0) {
        ljs[0] = cl2[nj[0]]; ljs[1] = cr2[nj[0]];
        ljs[2] = cl2[nj[1]]; ljs[3] = cr2[nj[1]];
        ljs[4] = cl2[nj[2]]; ljs[5] = cr2[nj[2]];
        ljs[6] = cl2[nj[3]]; ljs[7] = cr2[nj[3]];
        ljs[8] = cl2[nj[4]]; ljs[9] = cr2[nj[4]];
        ljs[10] = cs1[m0];   ljs[11] = cs1[m1];
    }

    // ---- preloads (scalars, vec triplets) ----
    const float aLv = aL[0], a2v = a2[0], a1v = a1[0], a0v = a0[0];
    const float wp0 = Wp[kk * 3 + 0], wp1 = Wp[kk * 3 + 1], wp2 = Wp[kk * 3 + 2];
    const float bpv = bp[kk];
    const float bb2v = bb2[kk], bb1v = bb1[kk], bs1v = bs1[kk];
    const float bb0v = bb0[kk], bs0v = bs0[kk];
    float v2r[5][3], v1r[2][3], v0r[3];
#pragma unroll
    for (int j = 0; j < 5; ++j) {
        size_t vb = ((size_t)b * N2 + nj[j]) * 3;
        v2r[j][0] = vec2[vb]; v2r[j][1] = vec2[vb + 1]; v2r[j][2] = vec2[vb + 2];
    }
    {
        size_t vb0 = ((size_t)b * N1 + m0) * 3, vb1 = ((size_t)b * N1 + m1) * 3;
        v1r[0][0] = vec1[vb0]; v1r[0][1] = vec1[vb0 + 1]; v1r[0][2] = vec1[vb0 + 2];
        v1r[1][0] = vec1[vb1]; v1r[1][1] = vec1[vb1 + 1]; v1r[1][2] = vec1[vb1 + 2];
    }
    v0r[0] = vec0[b * 3]; v0r[1] = vec0[b * 3 + 1]; v0r[2] = vec0[b * 3 + 2];

    // ---- preload sampled-linear weights (used at layer boundaries) ----
    float4 ws1v[8], ws0v[8];
#pragma unroll
    for (int i = 0; i < 8; ++i) {
        ws1v[i] = *reinterpret_cast<const float4*>(Ws1 + k * 256 + ((i * 8 + u) << 2));
        ws0v[i] = *reinterpret_cast<const float4*>(Ws0 + k * 256 + ((i * 8 + u) << 2));
    }

    // ---- depth-3 weight pipeline: 4 rotating register slots, all static ----
    float4 w[4][3];
    load_w3(Wb2, 0, k, u, w[0]);
    load_w3(Wb2, 1, k, u, w[1]);
    load_w3(Wb2, 2, k, u, w[2]);

    __syncthreads();                      // ljs visible

    // ---- leaf rows ----
    for (int idx = t; idx < 12 * DIM; idx += 1024) {
        int r = idx >> 7;
        size_t pb = ((size_t)b * N3 + ljs[r]) * 3;
        float p0 = points[pb], p1 = points[pb + 1], p2 = points[pb + 2];
        leaf[r][kk] = prelu(p0 * wp0 + p1 * wp1 + p2 * wp2 + bpv, aLv);
    }
    __syncthreads();                      // leaf visible

    // ================ layer 2: 5 nodes (global chunks 0..7) =================
    float acc2[5][3] = {};
#pragma unroll
    for (int c = 0; c < 8; ++c) {
        if (c < 5) load_w3(Wb2, c + 3, k, u, w[(c + 3) & 3]);
        else       load_w3(Wb1, c - 5, k, u, w[(c + 3) & 3]);  // cross-layer
        bilin_chunk_reg<5>(w[c & 3], c, &leaf[0][0], u, acc2);
    }
#pragma unroll
    for (int j = 0; j < 5; ++j) {
        float z = v2r[j][0] * acc2[j][0] + v2r[j][1] * acc2[j][1] +
                  v2r[j][2] * acc2[j][2];
        part[(u * 5 + j) * PSTR + k] = z;
    }
    __syncthreads();
    reduce_part<5>(part, bb2v, a2v, &h2s[0][0], t);
    __syncthreads();

    // ================ layer 1 bilinear: 2 nodes (chunks 8..15) ==============
    float acc1[2][3] = {};
#pragma unroll
    for (int c = 0; c < 8; ++c) {
        if (c < 5) load_w3(Wb1, c + 3, k, u, w[(c + 3) & 3]);
        else       load_w3(Wb0, c - 5, k, u, w[(c + 3) & 3]);  // prefetch root
        bilin_chunk_reg<2>(w[c & 3], c, &h2s[0][0], u, acc1);
    }
#pragma unroll
    for (int n = 0; n < 2; ++n) {
        float z = v1r[n][0] * acc1[n][0] + v1r[n][1] * acc1[n][1] +
                  v1r[n][2] * acc1[n][2];
        part[(u * 2 + n) * PSTR + k] = z;
    }
    __syncthreads();
    reduce_part<2>(part, bb1v, a1v, &t1s[0][0], t);
    __syncthreads();

    // ---- layer 1 sampled linear (register weights, preloaded) ----
    {
        const float* x0[2] = { &t1s[0][0], &t1s[1][0] };
        const float* x1[2] = { &leaf[10][0], &leaf[11][0] };
        linear_stage_pre<2>(ws1v, x0, x1, part, k, u);
    }
    __syncthreads();
    reduce_part<2>(part, bs1v, a1v, &h1s[0][0], t);
    __syncthreads();

    // ================ root bilinear: 1 node (chunks 16..23) =================
    float acc0[1][3] = {};
#pragma unroll
    for (int c = 0; c < 8; ++c) {
        if (c < 5) load_w3(Wb0, c + 3, k, u, w[(c + 3) & 3]);
        bilin_chunk_reg<1>(w[c & 3], c, &h1s[0][0], u, acc0);
    }
    {
        float z = v0r[0] * acc0[0][0] + v0r[1] * acc0[0][1] + v0r[2] * acc0[0][2];
        part[u * PSTR + k] = z;
    }
    __syncthreads();
    reduce_part<1>(part, bb0v, a0v, &h0s[0], t);
    __syncthreads();

    // ---- root sampled linear -> output ----
    {
        const float* x0[1] = { &h0s[0] };
        const float* x1[1] = { &h2s[4][0] };
        linear_stage_pre<1>(ws0v, x0, x1, part, k, u);
    }
    __syncthreads();
    if (t < DIM) {
        float p0 = part[0 * PSTR + t], p1 = part[1 * PSTR + t];
        float p2 = part[2 * PSTR + t], p3 = part[3 * PSTR + t];
        float p4 = part[4 * PSTR + t], p5 = part[5 * PSTR + t];
        float p6 = part[6 * PSTR + t], p7 = part[7 * PSTR + t];
        float s = ((p0 + p1) + (p2 + p3)) + ((p4 + p5) + (p6 + p7));
        out[(size_t)b * DIM + t] = prelu(s + bs0v, a0v);
    }
}

// ---------------- launch ---------------------------------------------------
extern "C" void kernel_launch(void* const* d_in, const int* in_sizes, int n_in,
                              void* d_out, int out_size, void* d_ws, size_t ws_size,
                              hipStream_t stream)
{
    const float* points = (const float*)d_in[0];
    const float* vec2   = (const float*)d_in[1];
    const float* vec1   = (const float*)d_in[2];
    const float* vec0   = (const float*)d_in[3];
    const float* Wp     = (const float*)d_in[4];
    const float* bp     = (const float*)d_in[5];
    const float* a_leaf = (const float*)d_in[6];
    const float* Wb2    = (const float*)d_in[7];
    const float* bb2    = (const float*)d_in[8];
    const float* a2     = (const float*)d_in[9];
    const float* Wb1    = (const float*)d_in[10];
    const float* bb1    = (const float*)d_in[11];
    const float* Ws1    = (const float*)d_in[12];
    const float* bs1    = (const float*)d_in[13];
    const float* a1     = (const float*)d_in[14];
    const float* Wb0    = (const float*)d_in[15];
    const float* bb0    = (const float*)d_in[16];
    const float* Ws0    = (const float*)d_in[17];
    const float* bs0    = (const float*)d_in[18];
    const float* a0     = (const float*)d_in[19];
    const int* cl2 = (const int*)d_in[20];
    const int* cr2 = (const int*)d_in[21];
    const int* cl1 = (const int*)d_in[22];
    const int* cr1 = (const int*)d_in[23];
    const int* cs1 = (const int*)d_in[24];
    const int* cl0 = (const int*)d_in[25];
    const int* cr0 = (const int*)d_in[26];
    const int* cs0 = (const int*)d_in[27];

    const int B = 8, N3 = 131072, N2 = 65536, N1 = 1024;
    (void)d_ws; (void)ws_size; (void)in_sizes; (void)n_in; (void)out_size;

    encoder_fused<<<B, 1024, 0, stream>>>(
        points, vec2, vec1, vec0,
        Wp, bp, a_leaf,
        Wb2, bb2, a2,
        Wb1, bb1, Ws1, bs1, a1,
        Wb0, bb0, Ws0, bs0, a0,
        cl2, cr2, cl1, cr1, cs1, cl0, cr0, cs0,
        (float*)d_out, N3, N2, N1);
}

// Round 13
// 19.493 us; speedup vs baseline: 1.4995x; 1.4963x over previous
//
#include <hip/hip_runtime.h>
#include <hip/hip_bf16.h>
#include <cstdint>

#define DIM 128
#define PSTR 132   // part[] row stride: 128+4 pad -> 2-way (free) bank access

__device__ __forceinline__ float prelu(float x, float a) {
    return x >= 0.f ? x : a * x;
}

// ---- per-thread weight fragment: 12 floats, PRIVATE to thread (k,u) ----
// Chunk c covers d in [32c,32c+32); thread (k,u) owns d-slice [32c+4u, +4),
// i.e. floats W[k*768 + c*96 + u*12 .. +11]. No LDS, no swizzle, no asm.
__device__ __forceinline__ void load_w3(const float* __restrict__ W, int c,
                                        int k, int u, float4 w[3]) {
    const float* p = W + (size_t)k * 768 + c * 96 + u * 12;
    w[0] = *reinterpret_cast<const float4*>(p);
    w[1] = *reinterpret_cast<const float4*>(p + 4);
    w[2] = *reinterpret_cast<const float4*>(p + 8);
}

// One 32-d chunk of bilinear accumulation from register weights.
// (Bit-exact verified in rounds 10/12.)
template<int J>
__device__ __forceinline__ void bilin_chunk_reg(const float4 w[3], int c,
                                                const float* xbase, int u,
                                                float acc[][3]) {
    const float wf[12] = { w[0].x, w[0].y, w[0].z, w[0].w,
                           w[1].x, w[1].y, w[1].z, w[1].w,
                           w[2].x, w[2].y, w[2].z, w[2].w };
    const int inner = ((c & 3) << 5) + (u << 2);
    const int half = c >> 2;   // which 128-row of the 256-wide concat
#pragma unroll
    for (int j = 0; j < J; ++j) {
        float4 xv = *reinterpret_cast<const float4*>(
            xbase + (2 * j + half) * 128 + inner);
        const float xf[4] = { xv.x, xv.y, xv.z, xv.w };
#pragma unroll
        for (int dl = 0; dl < 4; ++dl)
#pragma unroll
            for (int v = 0; v < 3; ++v)
                acc[j][v] += wf[dl * 3 + v] * xf[dl];
    }
}

// Epilogue: pairwise tree over the 8 u-slices (part stride PSTR).
template<int ROWS>
__device__ __forceinline__ void reduce_part(const float* part, float biasv,
                                            float aval, float* dst, int t) {
    if (t < ROWS * 128) {
        int r = t >> 7, kk = t & 127;
        float p0 = part[(0 * ROWS + r) * PSTR + kk];
        float p1 = part[(1 * ROWS + r) * PSTR + kk];
        float p2 = part[(2 * ROWS + r) * PSTR + kk];
        float p3 = part[(3 * ROWS + r) * PSTR + kk];
        float p4 = part[(4 * ROWS + r) * PSTR + kk];
        float p5 = part[(5 * ROWS + r) * PSTR + kk];
        float p6 = part[(6 * ROWS + r) * PSTR + kk];
        float p7 = part[(7 * ROWS + r) * PSTR + kk];
        float s = ((p0 + p1) + (p2 + p3)) + ((p4 + p5) + (p6 + p7));
        dst[r * 128 + kk] = prelu(s + biasv, aval);
    }
}

// Round-10 sampled linear: weights loaded AT USE (keeps register demand low;
// two exposed L3 hits total, ~0.4us — cheaper than spilling).
template<int NODES>
__device__ __forceinline__ void linear_stage(const float* __restrict__ Wsg,
                                             const float* const* x0,
                                             const float* const* x1,
                                             float* part, int k, int u) {
    float4 wv[8];
#pragma unroll
    for (int i = 0; i < 8; ++i)
        wv[i] = *reinterpret_cast<const float4*>(Wsg + k * 256 + ((i * 8 + u) << 2));
#pragma unroll
    for (int n = 0; n < NODES; ++n) {
        float acc = 0.f;
#pragma unroll
        for (int i = 0; i < 8; ++i) {
            const float* xr = (i < 4) ? (x0[n] + (i << 5) + (u << 2))
                                      : (x1[n] + ((i - 4) << 5) + (u << 2));
            float4 xv = *reinterpret_cast<const float4*>(xr);
            acc += wv[i].x * xv.x + wv[i].y * xv.y + wv[i].z * xv.z + wv[i].w * xv.w;
        }
        part[(u * NODES + n) * PSTR + k] = acc;
    }
}

// 1024 threads = 16 waves = 4 waves/SIMD -> 1 block/CU is the only possible
// occupancy; declare min 4 waves/EU so the allocator uses the full 128-VGPR
// physical cap instead of capping at 64 and SPILLING (round-12 regression:
// +0.6MB scratch FETCH, +1.2MB scratch WRITE, 19.9->29.2us).
__global__ __launch_bounds__(1024, 4) void encoder_fused(
    const float* __restrict__ points,
    const float* __restrict__ vec2, const float* __restrict__ vec1,
    const float* __restrict__ vec0,
    const float* __restrict__ Wp,  const float* __restrict__ bp,
    const float* __restrict__ aL,
    const float* __restrict__ Wb2, const float* __restrict__ bb2,
    const float* __restrict__ a2,
    const float* __restrict__ Wb1, const float* __restrict__ bb1,
    const float* __restrict__ Ws1, const float* __restrict__ bs1,
    const float* __restrict__ a1,
    const float* __restrict__ Wb0, const float* __restrict__ bb0,
    const float* __restrict__ Ws0, const float* __restrict__ bs0,
    const float* __restrict__ a0,
    const int* __restrict__ cl2, const int* __restrict__ cr2,
    const int* __restrict__ cl1, const int* __restrict__ cr1,
    const int* __restrict__ cs1,
    const int* __restrict__ cl0, const int* __restrict__ cr0,
    const int* __restrict__ cs0,
    float* __restrict__ out,
    int N3, int N2, int N1)
{
    __shared__ float leaf[12][DIM];
    __shared__ float h2s[5][DIM];
    __shared__ float t1s[2][DIM];
    __shared__ float h1s[2][DIM];
    __shared__ float h0s[DIM];
    __shared__ float part[8 * 5 * PSTR];
    __shared__ int   ljs[12];

    const int b = blockIdx.x;
    const int t = threadIdx.x;
    const int k  = t >> 3;    // output channel 0..127
    const int u  = t & 7;     // d-subchunk 0..7
    const int kk = t & 127;

    // ---- uniform index chain ----
    const int m0 = cl0[0], m1 = cr0[0];
    int nj[5];
    nj[0] = cl1[m0]; nj[1] = cr1[m0];
    nj[2] = cl1[m1]; nj[3] = cr1[m1];
    nj[4] = cs0[0];
    if (t == 0) {
        ljs[0] = cl2[nj[0]]; ljs[1] = cr2[nj[0]];
        ljs[2] = cl2[nj[1]]; ljs[3] = cr2[nj[1]];
        ljs[4] = cl2[nj[2]]; ljs[5] = cr2[nj[2]];
        ljs[6] = cl2[nj[3]]; ljs[7] = cr2[nj[3]];
        ljs[8] = cl2[nj[4]]; ljs[9] = cr2[nj[4]];
        ljs[10] = cs1[m0];   ljs[11] = cs1[m1];
    }

    // ---- preloads (scalars, vec triplets) ----
    const float aLv = aL[0], a2v = a2[0], a1v = a1[0], a0v = a0[0];
    const float wp0 = Wp[kk * 3 + 0], wp1 = Wp[kk * 3 + 1], wp2 = Wp[kk * 3 + 2];
    const float bpv = bp[kk];
    const float bb2v = bb2[kk], bb1v = bb1[kk], bs1v = bs1[kk];
    const float bb0v = bb0[kk], bs0v = bs0[kk];
    float v2r[5][3], v1r[2][3], v0r[3];
#pragma unroll
    for (int j = 0; j < 5; ++j) {
        size_t vb = ((size_t)b * N2 + nj[j]) * 3;
        v2r[j][0] = vec2[vb]; v2r[j][1] = vec2[vb + 1]; v2r[j][2] = vec2[vb + 2];
    }
    {
        size_t vb0 = ((size_t)b * N1 + m0) * 3, vb1 = ((size_t)b * N1 + m1) * 3;
        v1r[0][0] = vec1[vb0]; v1r[0][1] = vec1[vb0 + 1]; v1r[0][2] = vec1[vb0 + 2];
        v1r[1][0] = vec1[vb1]; v1r[1][1] = vec1[vb1 + 1]; v1r[1][2] = vec1[vb1 + 2];
    }
    v0r[0] = vec0[b * 3]; v0r[1] = vec0[b * 3 + 1]; v0r[2] = vec0[b * 3 + 2];

    // ---- depth-3 weight pipeline: 4 rotating register slots, all static ----
    float4 w[4][3];
    load_w3(Wb2, 0, k, u, w[0]);
    load_w3(Wb2, 1, k, u, w[1]);
    load_w3(Wb2, 2, k, u, w[2]);

    __syncthreads();                      // ljs visible

    // ---- leaf rows ----
    for (int idx = t; idx < 12 * DIM; idx += 1024) {
        int r = idx >> 7;
        size_t pb = ((size_t)b * N3 + ljs[r]) * 3;
        float p0 = points[pb], p1 = points[pb + 1], p2 = points[pb + 2];
        leaf[r][kk] = prelu(p0 * wp0 + p1 * wp1 + p2 * wp2 + bpv, aLv);
    }
    __syncthreads();                      // leaf visible

    // ================ layer 2: 5 nodes (global chunks 0..7) =================
    float acc2[5][3] = {};
#pragma unroll
    for (int c = 0; c < 8; ++c) {
        if (c < 5) load_w3(Wb2, c + 3, k, u, w[(c + 3) & 3]);
        else       load_w3(Wb1, c - 5, k, u, w[(c + 3) & 3]);  // cross-layer
        bilin_chunk_reg<5>(w[c & 3], c, &leaf[0][0], u, acc2);
    }
#pragma unroll
    for (int j = 0; j < 5; ++j) {
        float z = v2r[j][0] * acc2[j][0] + v2r[j][1] * acc2[j][1] +
                  v2r[j][2] * acc2[j][2];
        part[(u * 5 + j) * PSTR + k] = z;
    }
    __syncthreads();
    reduce_part<5>(part, bb2v, a2v, &h2s[0][0], t);
    __syncthreads();

    // ================ layer 1 bilinear: 2 nodes (chunks 8..15) ==============
    float acc1[2][3] = {};
#pragma unroll
    for (int c = 0; c < 8; ++c) {
        if (c < 5) load_w3(Wb1, c + 3, k, u, w[(c + 3) & 3]);
        else       load_w3(Wb0, c - 5, k, u, w[(c + 3) & 3]);  // prefetch root
        bilin_chunk_reg<2>(w[c & 3], c, &h2s[0][0], u, acc1);
    }
#pragma unroll
    for (int n = 0; n < 2; ++n) {
        float z = v1r[n][0] * acc1[n][0] + v1r[n][1] * acc1[n][1] +
                  v1r[n][2] * acc1[n][2];
        part[(u * 2 + n) * PSTR + k] = z;
    }
    __syncthreads();
    reduce_part<2>(part, bb1v, a1v, &t1s[0][0], t);
    __syncthreads();

    // ---- layer 1 sampled linear (weights at use) ----
    {
        const float* x0[2] = { &t1s[0][0], &t1s[1][0] };
        const float* x1[2] = { &leaf[10][0], &leaf[11][0] };
        linear_stage<2>(Ws1, x0, x1, part, k, u);
    }
    __syncthreads();
    reduce_part<2>(part, bs1v, a1v, &h1s[0][0], t);
    __syncthreads();

    // ================ root bilinear: 1 node (chunks 16..23) =================
    float acc0[1][3] = {};
#pragma unroll
    for (int c = 0; c < 8; ++c) {
        if (c < 5) load_w3(Wb0, c + 3, k, u, w[(c + 3) & 3]);
        bilin_chunk_reg<1>(w[c & 3], c, &h1s[0][0], u, acc0);
    }
    {
        float z = v0r[0] * acc0[0][0] + v0r[1] * acc0[0][1] + v0r[2] * acc0[0][2];
        part[u * PSTR + k] = z;
    }
    __syncthreads();
    reduce_part<1>(part, bb0v, a0v, &h0s[0], t);
    __syncthreads();

    // ---- root sampled linear -> output ----
    {
        const float* x0[1] = { &h0s[0] };
        const float* x1[1] = { &h2s[4][0] };
        linear_stage<1>(Ws0, x0, x1, part, k, u);
    }
    __syncthreads();
    if (t < DIM) {
        float p0 = part[0 * PSTR + t], p1 = part[1 * PSTR + t];
        float p2 = part[2 * PSTR + t], p3 = part[3 * PSTR + t];
        float p4 = part[4 * PSTR + t], p5 = part[5 * PSTR + t];
        float p6 = part[6 * PSTR + t], p7 = part[7 * PSTR + t];
        float s = ((p0 + p1) + (p2 + p3)) + ((p4 + p5) + (p6 + p7));
        out[(size_t)b * DIM + t] = prelu(s + bs0v, a0v);
    }
}

// ---------------- launch ---------------------------------------------------
extern "C" void kernel_launch(void* const* d_in, const int* in_sizes, int n_in,
                              void* d_out, int out_size, void* d_ws, size_t ws_size,
                              hipStream_t stream)
{
    const float* points = (const float*)d_in[0];
    const float* vec2   = (const float*)d_in[1];
    const float* vec1   = (const float*)d_in[2];
    const float* vec0   = (const float*)d_in[3];
    const float* Wp     = (const float*)d_in[4];
    const float* bp     = (const float*)d_in[5];
    const float* a_leaf = (const float*)d_in[6];
    const float* Wb2    = (const float*)d_in[7];
    const float* bb2    = (const float*)d_in[8];
    const float* a2     = (const float*)d_in[9];
    const float* Wb1    = (const float*)d_in[10];
    const float* bb1    = (const float*)d_in[11];
    const float* Ws1    = (const float*)d_in[12];
    const float* bs1    = (const float*)d_in[13];
    const float* a1     = (const float*)d_in[14];
    const float* Wb0    = (const float*)d_in[15];
    const float* bb0    = (const float*)d_in[16];
    const float* Ws0    = (const float*)d_in[17];
    const float* bs0    = (const float*)d_in[18];
    const float* a0     = (const float*)d_in[19];
    const int* cl2 = (const int*)d_in[20];
    const int* cr2 = (const int*)d_in[21];
    const int* cl1 = (const int*)d_in[22];
    const int* cr1 = (const int*)d_in[23];
    const int* cs1 = (const int*)d_in[24];
    const int* cl0 = (const int*)d_in[25];
    const int* cr0 = (const int*)d_in[26];
    const int* cs0 = (const int*)d_in[27];

    const int B = 8, N3 = 131072, N2 = 65536, N1 = 1024;
    (void)d_ws; (void)ws_size; (void)in_sizes; (void)n_in; (void)out_size;

    encoder_fused<<<B, 1024, 0, stream>>>(
        points, vec2, vec1, vec0,
        Wp, bp, a_leaf,
        Wb2, bb2, a2,
        Wb1, bb1, Ws1, bs1, a1,
        Wb0, bb0, Ws0, bs0, a0,
        cl2, cr2, cl1, cr1, cs1, cl0, cr0, cs0,
        (float*)d_out, N3, N2, N1);
}

// Round 14
// 19.405 us; speedup vs baseline: 1.5063x; 1.0045x over previous
//
#include <hip/hip_runtime.h>
#include <hip/hip_bf16.h>
#include <cstdint>

#define DIM 128
#define PSTR 132   // part[] row stride: 128+4 pad -> 2-way (free) bank access

__device__ __forceinline__ float prelu(float x, float a) {
    return x >= 0.f ? x : a * x;
}

// ---- per-thread weight fragment: 12 floats, PRIVATE to thread (k,u) ----
// Chunk c covers d in [32c,32c+32); thread (k,u) owns d-slice [32c+4u, +4),
// i.e. floats W[k*768 + c*96 + u*12 .. +11]. No LDS, no swizzle, no asm.
__device__ __forceinline__ void load_w3(const float* __restrict__ W, int c,
                                        int k, int u, float4 w[3]) {
    const float* p = W + (size_t)k * 768 + c * 96 + u * 12;
    w[0] = *reinterpret_cast<const float4*>(p);
    w[1] = *reinterpret_cast<const float4*>(p + 4);
    w[2] = *reinterpret_cast<const float4*>(p + 8);
}

// One 32-d chunk of bilinear accumulation from register weights.
// (Bit-exact verified in rounds 10/12.)
template<int J>
__device__ __forceinline__ void bilin_chunk_reg(const float4 w[3], int c,
                                                const float* xbase, int u,
                                                float acc[][3]) {
    const float wf[12] = { w[0].x, w[0].y, w[0].z, w[0].w,
                           w[1].x, w[1].y, w[1].z, w[1].w,
                           w[2].x, w[2].y, w[2].z, w[2].w };
    const int inner = ((c & 3) << 5) + (u << 2);
    const int half = c >> 2;   // which 128-row of the 256-wide concat
#pragma unroll
    for (int j = 0; j < J; ++j) {
        float4 xv = *reinterpret_cast<const float4*>(
            xbase + (2 * j + half) * 128 + inner);
        const float xf[4] = { xv.x, xv.y, xv.z, xv.w };
#pragma unroll
        for (int dl = 0; dl < 4; ++dl)
#pragma unroll
            for (int v = 0; v < 3; ++v)
                acc[j][v] += wf[dl * 3 + v] * xf[dl];
    }
}

// Epilogue: pairwise tree over the 8 u-slices (part stride PSTR).
template<int ROWS>
__device__ __forceinline__ void reduce_part(const float* part, float biasv,
                                            float aval, float* dst, int t) {
    if (t < ROWS * 128) {
        int r = t >> 7, kk = t & 127;
        float p0 = part[(0 * ROWS + r) * PSTR + kk];
        float p1 = part[(1 * ROWS + r) * PSTR + kk];
        float p2 = part[(2 * ROWS + r) * PSTR + kk];
        float p3 = part[(3 * ROWS + r) * PSTR + kk];
        float p4 = part[(4 * ROWS + r) * PSTR + kk];
        float p5 = part[(5 * ROWS + r) * PSTR + kk];
        float p6 = part[(6 * ROWS + r) * PSTR + kk];
        float p7 = part[(7 * ROWS + r) * PSTR + kk];
        float s = ((p0 + p1) + (p2 + p3)) + ((p4 + p5) + (p6 + p7));
        dst[r * 128 + kk] = prelu(s + biasv, aval);
    }
}

// Round-10 sampled linear: weights loaded AT USE (keeps register demand low;
// two exposed L3 hits total, ~0.4us — cheaper than spilling).
template<int NODES>
__device__ __forceinline__ void linear_stage(const float* __restrict__ Wsg,
                                             const float* const* x0,
                                             const float* const* x1,
                                             float* part, int k, int u) {
    float4 wv[8];
#pragma unroll
    for (int i = 0; i < 8; ++i)
        wv[i] = *reinterpret_cast<const float4*>(Wsg + k * 256 + ((i * 8 + u) << 2));
#pragma unroll
    for (int n = 0; n < NODES; ++n) {
        float acc = 0.f;
#pragma unroll
        for (int i = 0; i < 8; ++i) {
            const float* xr = (i < 4) ? (x0[n] + (i << 5) + (u << 2))
                                      : (x1[n] + ((i - 4) << 5) + (u << 2));
            float4 xv = *reinterpret_cast<const float4*>(xr);
            acc += wv[i].x * xv.x + wv[i].y * xv.y + wv[i].z * xv.z + wv[i].w * xv.w;
        }
        part[(u * NODES + n) * PSTR + k] = acc;
    }
}

// 1024 threads = 16 waves = 4 waves/SIMD -> 1 block/CU is the only possible
// occupancy; declare min 4 waves/EU so the allocator uses the full 128-VGPR
// physical cap instead of capping at 64 and SPILLING (round-12 regression:
// +0.6MB scratch FETCH, +1.2MB scratch WRITE, 19.9->29.2us).
__global__ __launch_bounds__(1024, 4) void encoder_fused(
    const float* __restrict__ points,
    const float* __restrict__ vec2, const float* __restrict__ vec1,
    const float* __restrict__ vec0,
    const float* __restrict__ Wp,  const float* __restrict__ bp,
    const float* __restrict__ aL,
    const float* __restrict__ Wb2, const float* __restrict__ bb2,
    const float* __restrict__ a2,
    const float* __restrict__ Wb1, const float* __restrict__ bb1,
    const float* __restrict__ Ws1, const float* __restrict__ bs1,
    const float* __restrict__ a1,
    const float* __restrict__ Wb0, const float* __restrict__ bb0,
    const float* __restrict__ Ws0, const float* __restrict__ bs0,
    const float* __restrict__ a0,
    const int* __restrict__ cl2, const int* __restrict__ cr2,
    const int* __restrict__ cl1, const int* __restrict__ cr1,
    const int* __restrict__ cs1,
    const int* __restrict__ cl0, const int* __restrict__ cr0,
    const int* __restrict__ cs0,
    float* __restrict__ out,
    int N3, int N2, int N1)
{
    __shared__ float leaf[12][DIM];
    __shared__ float h2s[5][DIM];
    __shared__ float t1s[2][DIM];
    __shared__ float h1s[2][DIM];
    __shared__ float h0s[DIM];
    __shared__ float part[8 * 5 * PSTR];
    __shared__ int   ljs[12];

    const int b = blockIdx.x;
    const int t = threadIdx.x;
    const int k  = t >> 3;    // output channel 0..127
    const int u  = t & 7;     // d-subchunk 0..7
    const int kk = t & 127;

    // ---- uniform index chain ----
    const int m0 = cl0[0], m1 = cr0[0];
    int nj[5];
    nj[0] = cl1[m0]; nj[1] = cr1[m0];
    nj[2] = cl1[m1]; nj[3] = cr1[m1];
    nj[4] = cs0[0];
    if (t == 0) {
        ljs[0] = cl2[nj[0]]; ljs[1] = cr2[nj[0]];
        ljs[2] = cl2[nj[1]]; ljs[3] = cr2[nj[1]];
        ljs[4] = cl2[nj[2]]; ljs[5] = cr2[nj[2]];
        ljs[6] = cl2[nj[3]]; ljs[7] = cr2[nj[3]];
        ljs[8] = cl2[nj[4]]; ljs[9] = cr2[nj[4]];
        ljs[10] = cs1[m0];   ljs[11] = cs1[m1];
    }

    // ---- preloads (scalars, vec triplets) ----
    const float aLv = aL[0], a2v = a2[0], a1v = a1[0], a0v = a0[0];
    const float wp0 = Wp[kk * 3 + 0], wp1 = Wp[kk * 3 + 1], wp2 = Wp[kk * 3 + 2];
    const float bpv = bp[kk];
    const float bb2v = bb2[kk], bb1v = bb1[kk], bs1v = bs1[kk];
    const float bb0v = bb0[kk], bs0v = bs0[kk];
    float v2r[5][3], v1r[2][3], v0r[3];
#pragma unroll
    for (int j = 0; j < 5; ++j) {
        size_t vb = ((size_t)b * N2 + nj[j]) * 3;
        v2r[j][0] = vec2[vb]; v2r[j][1] = vec2[vb + 1]; v2r[j][2] = vec2[vb + 2];
    }
    {
        size_t vb0 = ((size_t)b * N1 + m0) * 3, vb1 = ((size_t)b * N1 + m1) * 3;
        v1r[0][0] = vec1[vb0]; v1r[0][1] = vec1[vb0 + 1]; v1r[0][2] = vec1[vb0 + 2];
        v1r[1][0] = vec1[vb1]; v1r[1][1] = vec1[vb1 + 1]; v1r[1][2] = vec1[vb1 + 2];
    }
    v0r[0] = vec0[b * 3]; v0r[1] = vec0[b * 3 + 1]; v0r[2] = vec0[b * 3 + 2];

    // ---- depth-3 weight pipeline: 4 rotating register slots, all static ----
    float4 w[4][3];
    load_w3(Wb2, 0, k, u, w[0]);
    load_w3(Wb2, 1, k, u, w[1]);
    load_w3(Wb2, 2, k, u, w[2]);

    __syncthreads();                      // ljs visible

    // ---- leaf rows ----
    for (int idx = t; idx < 12 * DIM; idx += 1024) {
        int r = idx >> 7;
        size_t pb = ((size_t)b * N3 + ljs[r]) * 3;
        float p0 = points[pb], p1 = points[pb + 1], p2 = points[pb + 2];
        leaf[r][kk] = prelu(p0 * wp0 + p1 * wp1 + p2 * wp2 + bpv, aLv);
    }
    __syncthreads();                      // leaf visible

    // ================ layer 2: 5 nodes (global chunks 0..7) =================
    float acc2[5][3] = {};
#pragma unroll
    for (int c = 0; c < 8; ++c) {
        if (c < 5) load_w3(Wb2, c + 3, k, u, w[(c + 3) & 3]);
        else       load_w3(Wb1, c - 5, k, u, w[(c + 3) & 3]);  // cross-layer
        bilin_chunk_reg<5>(w[c & 3], c, &leaf[0][0], u, acc2);
    }
#pragma unroll
    for (int j = 0; j < 5; ++j) {
        float z = v2r[j][0] * acc2[j][0] + v2r[j][1] * acc2[j][1] +
                  v2r[j][2] * acc2[j][2];
        part[(u * 5 + j) * PSTR + k] = z;
    }
    __syncthreads();
    reduce_part<5>(part, bb2v, a2v, &h2s[0][0], t);
    __syncthreads();

    // ================ layer 1 bilinear: 2 nodes (chunks 8..15) ==============
    float acc1[2][3] = {};
#pragma unroll
    for (int c = 0; c < 8; ++c) {
        if (c < 5) load_w3(Wb1, c + 3, k, u, w[(c + 3) & 3]);
        else       load_w3(Wb0, c - 5, k, u, w[(c + 3) & 3]);  // prefetch root
        bilin_chunk_reg<2>(w[c & 3], c, &h2s[0][0], u, acc1);
    }
#pragma unroll
    for (int n = 0; n < 2; ++n) {
        float z = v1r[n][0] * acc1[n][0] + v1r[n][1] * acc1[n][1] +
                  v1r[n][2] * acc1[n][2];
        part[(u * 2 + n) * PSTR + k] = z;
    }
    __syncthreads();
    reduce_part<2>(part, bb1v, a1v, &t1s[0][0], t);
    __syncthreads();

    // ---- layer 1 sampled linear (weights at use) ----
    {
        const float* x0[2] = { &t1s[0][0], &t1s[1][0] };
        const float* x1[2] = { &leaf[10][0], &leaf[11][0] };
        linear_stage<2>(Ws1, x0, x1, part, k, u);
    }
    __syncthreads();
    reduce_part<2>(part, bs1v, a1v, &h1s[0][0], t);
    __syncthreads();

    // ================ root bilinear: 1 node (chunks 16..23) =================
    float acc0[1][3] = {};
#pragma unroll
    for (int c = 0; c < 8; ++c) {
        if (c < 5) load_w3(Wb0, c + 3, k, u, w[(c + 3) & 3]);
        bilin_chunk_reg<1>(w[c & 3], c, &h1s[0][0], u, acc0);
    }
    {
        float z = v0r[0] * acc0[0][0] + v0r[1] * acc0[0][1] + v0r[2] * acc0[0][2];
        part[u * PSTR + k] = z;
    }
    __syncthreads();
    reduce_part<1>(part, bb0v, a0v, &h0s[0], t);
    __syncthreads();

    // ---- root sampled linear -> output ----
    {
        const float* x0[1] = { &h0s[0] };
        const float* x1[1] = { &h2s[4][0] };
        linear_stage<1>(Ws0, x0, x1, part, k, u);
    }
    __syncthreads();
    if (t < DIM) {
        float p0 = part[0 * PSTR + t], p1 = part[1 * PSTR + t];
        float p2 = part[2 * PSTR + t], p3 = part[3 * PSTR + t];
        float p4 = part[4 * PSTR + t], p5 = part[5 * PSTR + t];
        float p6 = part[6 * PSTR + t], p7 = part[7 * PSTR + t];
        float s = ((p0 + p1) + (p2 + p3)) + ((p4 + p5) + (p6 + p7));
        out[(size_t)b * DIM + t] = prelu(s + bs0v, a0v);
    }
}

// ---------------- launch ---------------------------------------------------
extern "C" void kernel_launch(void* const* d_in, const int* in_sizes, int n_in,
                              void* d_out, int out_size, void* d_ws, size_t ws_size,
                              hipStream_t stream)
{
    const float* points = (const float*)d_in[0];
    const float* vec2   = (const float*)d_in[1];
    const float* vec1   = (const float*)d_in[2];
    const float* vec0   = (const float*)d_in[3];
    const float* Wp     = (const float*)d_in[4];
    const float* bp     = (const float*)d_in[5];
    const float* a_leaf = (const float*)d_in[6];
    const float* Wb2    = (const float*)d_in[7];
    const float* bb2    = (const float*)d_in[8];
    const float* a2     = (const float*)d_in[9];
    const float* Wb1    = (const float*)d_in[10];
    const float* bb1    = (const float*)d_in[11];
    const float* Ws1    = (const float*)d_in[12];
    const float* bs1    = (const float*)d_in[13];
    const float* a1     = (const float*)d_in[14];
    const float* Wb0    = (const float*)d_in[15];
    const float* bb0    = (const float*)d_in[16];
    const float* Ws0    = (const float*)d_in[17];
    const float* bs0    = (const float*)d_in[18];
    const float* a0     = (const float*)d_in[19];
    const int* cl2 = (const int*)d_in[20];
    const int* cr2 = (const int*)d_in[21];
    const int* cl1 = (const int*)d_in[22];
    const int* cr1 = (const int*)d_in[23];
    const int* cs1 = (const int*)d_in[24];
    const int* cl0 = (const int*)d_in[25];
    const int* cr0 = (const int*)d_in[26];
    const int* cs0 = (const int*)d_in[27];

    const int B = 8, N3 = 131072, N2 = 65536, N1 = 1024;
    (void)d_ws; (void)ws_size; (void)in_sizes; (void)n_in; (void)out_size;

    encoder_fused<<<B, 1024, 0, stream>>>(
        points, vec2, vec1, vec0,
        Wp, bp, a_leaf,
        Wb2, bb2, a2,
        Wb1, bb1, Ws1, bs1, a1,
        Wb0, bb0, Ws0, bs0, a0,
        cl2, cr2, cl1, cr1, cs1, cl0, cr0, cs0,
        (float*)d_out, N3, N2, N1);
}